// Round 1
// baseline (1837.118 us; speedup 1.0000x reference)
//
#include <hip/hip_runtime.h>
#include <stdint.h>

// Problem constants
#define BATCH 16
#define NPTS 4096
#define DFEAT 128
#define NGRP 1024
#define KNNK 16
#define DOUT_CH 256
#define KPAD 160          // 131 padded to 5*32 for MFMA K
#define APAD 168          // LDS row stride (pad for banks)
#define NGROUPS (BATCH*NGRP)            // 16384
#define MROWS (NGROUPS*KNNK)            // 262144
#define GEMM_BLOCKS (NGROUPS/8)         // 2048
#define OUT_FEAT_ELEMS (NGROUPS*DOUT_CH) // 4194304

typedef __attribute__((ext_vector_type(8))) short s16x8;
typedef __attribute__((ext_vector_type(8))) __bf16 bf16x8;
typedef __attribute__((ext_vector_type(4))) float f32x4;

union V8U { s16x8 s; bf16x8 b; };

__device__ inline unsigned short f2bf(float f) {
  unsigned u = __float_as_uint(f);
  unsigned r = 0x7FFFu + ((u >> 16) & 1u);
  return (unsigned short)((u + r) >> 16);
}

// Bit-exact (vs jnp fp32, no-FMA) squared distance: ((dx*dx + dy*dy) + dz*dz)
__device__ inline float sqdist3(float ax, float ay, float az,
                                float bx, float by, float bz) {
  float dx = __fsub_rn(ax, bx);
  float dy = __fsub_rn(ay, by);
  float dz = __fsub_rn(az, bz);
  return __fadd_rn(__fadd_rn(__fmul_rn(dx, dx), __fmul_rn(dy, dy)), __fmul_rn(dz, dz));
}

// ---------------------------------------------------------------------------
// K1: FPS (blocks 0..15, one per batch) + W cast/permute/pad (block 16).
// Exact farthest-point sampling, deterministic start at point 0, lowest-index
// tie-break (matches jnp.argmax). Writes center coords straight into d_out.
// ---------------------------------------------------------------------------
__global__ __launch_bounds__(512)
void fps_wcast_kernel(const float* __restrict__ coord, const float* __restrict__ W,
                      float* __restrict__ out_coord, unsigned short* __restrict__ Wb)
{
  if (blockIdx.x >= BATCH) {
    // W: [256][131] fp32 -> Wb: [256][160] bf16, cols 0..127 = W[:,3:131] (features),
    // cols 128..130 = W[:,0:3] (coords), cols 131..159 = 0.
    for (int i = threadIdx.x; i < DOUT_CH * KPAD; i += 512) {
      int n = i / KPAD;
      int k = i - n * KPAD;
      float v = 0.f;
      if (k < 128)      v = W[n * 131 + 3 + k];
      else if (k < 131) v = W[n * 131 + (k - 128)];
      Wb[i] = f2bf(v);
    }
    return;
  }
  const int b = blockIdx.x;
  const int t = threadIdx.x;
  __shared__ float c3[NPTS * 3];
  __shared__ float swv[8];
  __shared__ int   swi[8];
  __shared__ int   swin;

  { // coalesced load of this batch's coords into LDS (layout-preserving)
    const float4* g4 = (const float4*)(coord + (size_t)b * NPTS * 3);
    float4* l4 = (float4*)c3;
    #pragma unroll
    for (int qq = 0; qq < 6; ++qq) l4[t + 512 * qq] = g4[t + 512 * qq];
  }
  __syncthreads();

  // thread t owns points p = t + 512*j (j ascending => idx ascending: tie-break ok)
  float px[8], py[8], pz[8], dist[8];
  #pragma unroll
  for (int j = 0; j < 8; ++j) {
    int p = t + 512 * j;
    px[j] = c3[3 * p]; py[j] = c3[3 * p + 1]; pz[j] = c3[3 * p + 2];
    dist[j] = __builtin_inff();
  }

  float* oc = out_coord + (size_t)b * NGRP * 3;
  if (t == 0) { oc[0] = c3[0]; oc[1] = c3[1]; oc[2] = c3[2]; }

  int last = 0;
  for (int i = 1; i < NGRP; ++i) {
    float lx = c3[3 * last], ly = c3[3 * last + 1], lz = c3[3 * last + 2];
    float bv = -1.f; int bidx = 0x7fffffff;
    #pragma unroll
    for (int j = 0; j < 8; ++j) {
      float d  = sqdist3(px[j], py[j], pz[j], lx, ly, lz);
      float nd = fminf(dist[j], d);
      dist[j] = nd;
      if (nd > bv) { bv = nd; bidx = t + 512 * j; }   // strict > keeps lowest idx
    }
    #pragma unroll
    for (int off = 1; off < 64; off <<= 1) {
      float ov = __shfl_xor(bv, off);
      int   oi = __shfl_xor(bidx, off);
      if (ov > bv || (ov == bv && oi < bidx)) { bv = ov; bidx = oi; }
    }
    if ((t & 63) == 0) { swv[t >> 6] = bv; swi[t >> 6] = bidx; }
    __syncthreads();
    if (t == 0) {
      float mv = swv[0]; int mi = swi[0];
      #pragma unroll
      for (int k = 1; k < 8; ++k)
        if (swv[k] > mv || (swv[k] == mv && swi[k] < mi)) { mv = swv[k]; mi = swi[k]; }
      swin = mi;
      oc[i * 3 + 0] = c3[3 * mi]; oc[i * 3 + 1] = c3[3 * mi + 1]; oc[i * 3 + 2] = c3[3 * mi + 2];
    }
    __syncthreads();
    last = swin;
  }
}

// ---------------------------------------------------------------------------
// K2: exact kNN (k=16). One wave per center; 2 centers per 128-thread block.
// Threshold T = 16th-smallest of per-lane minima (provable upper bound on true
// 16th distance) -> filter -> 16 exact argmin rounds with (d, idx) tie-break.
// ---------------------------------------------------------------------------
#define KNN_SLOTS 512
__global__ __launch_bounds__(128)
void knn_kernel(const float* __restrict__ coord, const float* __restrict__ cent,
                int* __restrict__ nidx)
{
  __shared__ float sd[2 * NPTS];
  __shared__ float svd[2 * KNN_SLOTS];
  __shared__ int   svi[2 * KNN_SLOTS];

  const int w = threadIdx.x >> 6;
  const int lane = threadIdx.x & 63;
  const int c = blockIdx.x * 2 + w;
  const int b = c >> 10;
  float* wd  = sd  + w * NPTS;
  float* wsd = svd + w * KNN_SLOTS;
  int*   wsi = svi + w * KNN_SLOTS;

  const float cx = cent[c * 3], cy = cent[c * 3 + 1], cz = cent[c * 3 + 2];
  const float* pc = coord + (size_t)b * NPTS * 3;

  float m = __builtin_inff();
  for (int tt = 0; tt < 64; ++tt) {
    int p = tt * 64 + lane;
    float d = sqdist3(cx, cy, cz, pc[3 * p], pc[3 * p + 1], pc[3 * p + 2]);
    wd[p] = d;
    m = fminf(m, d);
  }
  // radix-select the 16th smallest of the 64 lane minima (fp32 bits, all >= 0)
  unsigned mb = __float_as_uint(m);
  unsigned prefix = 0u;
  for (int bit = 30; bit >= 0; --bit) {
    unsigned trial = prefix | (1u << bit);
    unsigned long long ball = __ballot(mb < trial);
    if (__popcll(ball) < 16) prefix = trial;
  }
  const unsigned T = prefix;

  // compact survivors (d <= T); slot order == ascending point idx
  int base = 0;
  unsigned long long ltmask = (1ull << lane) - 1ull;
  for (int tt = 0; tt < 64; ++tt) {
    int p = tt * 64 + lane;
    float d = wd[p];
    bool keep = (__float_as_uint(d) <= T);
    unsigned long long mk = __ballot(keep);
    if (keep) {
      int pos = base + __popcll(mk & ltmask);
      if (pos < KNN_SLOTS) { wsd[pos] = d; wsi[pos] = p; }
    }
    base += __popcll(mk);
  }
  int S = base < KNN_SLOTS ? base : KNN_SLOTS;

  for (int r = 0; r < KNNK; ++r) {
    float bd = __builtin_inff(); int bs = 0x7fffffff;
    for (int s = lane; s < S; s += 64) {
      float d = wsd[s];
      if (d < bd) { bd = d; bs = s; }   // strict < keeps lowest slot/idx
    }
    #pragma unroll
    for (int off = 1; off < 64; off <<= 1) {
      float od = __shfl_xor(bd, off);
      int   os = __shfl_xor(bs, off);
      if (od < bd || (od == bd && os < bs)) { bd = od; bs = os; }
    }
    if (lane == 0) {
      nidx[c * KNNK + r] = wsi[bs];
      wsd[bs] = __builtin_inff();
    }
    __syncthreads();
  }
}

// ---------------------------------------------------------------------------
// K3: fused gather + bf16 MFMA GEMM + epilogue (max/min over K=16, channel
// sum/sumsq partials). Block = 8 groups (128 M-rows), 4 waves = 4x64 channels.
// W fragments held in registers; A (16x160 bf16) staged via LDS double-buffer.
// ---------------------------------------------------------------------------
__global__ __launch_bounds__(256)
void gemm_kernel(const float* __restrict__ feat, const float* __restrict__ coord,
                 const float* __restrict__ cent, const int* __restrict__ nidx,
                 const unsigned short* __restrict__ Wb,
                 float* __restrict__ psum, float* __restrict__ psumsq,
                 float* __restrict__ wmax, float* __restrict__ wmin)
{
  __shared__ unsigned short Abuf[2][16][APAD];
  const int tid = threadIdx.x;
  const int w = tid >> 6, lane = tid & 63;
  const int lr = lane & 15, q = lane >> 4;
  const int g0 = blockIdx.x * 8;
  const int b = g0 >> 10;

  // zero cols 128..159 of both buffers once (coords overwrite 128..130 per group)
  for (int i = tid; i < 2 * 16 * 32; i += 256) {
    int buf = i >> 9, rr = (i >> 5) & 15, cc = 128 + (i & 31);
    Abuf[buf][rr][cc] = 0;
  }

  // B fragments: B[k][n] supplied as Wb[n][k] row chunks (16B per lane)
  V8U bfrag[4][5];
  #pragma unroll
  for (int nt = 0; nt < 4; ++nt)
    #pragma unroll
    for (int kt = 0; kt < 5; ++kt) {
      int n = w * 64 + nt * 16 + lr;
      bfrag[nt][kt].s = *(const s16x8*)(Wb + n * KPAD + kt * 32 + q * 8);
    }

  float sum1[4] = {0, 0, 0, 0}, sum2[4] = {0, 0, 0, 0};

  auto stage = [&](int gi, int buf) {
    int g = g0 + gi;
    int r = tid >> 4, c16 = tid & 15;
    int np = nidx[g * 16 + r];
    const float* fr = feat + ((size_t)(b * NPTS + np)) * DFEAT + c16 * 8;
    float4 f0 = ((const float4*)fr)[0];
    float4 f1 = ((const float4*)fr)[1];
    s16x8 v;
    v[0] = f2bf(f0.x); v[1] = f2bf(f0.y); v[2] = f2bf(f0.z); v[3] = f2bf(f0.w);
    v[4] = f2bf(f1.x); v[5] = f2bf(f1.y); v[6] = f2bf(f1.z); v[7] = f2bf(f1.w);
    *(s16x8*)&Abuf[buf][r][c16 * 8] = v;
    if (tid < 16) {
      int np2 = nidx[g * 16 + tid];
      const float* p = coord + ((size_t)(b * NPTS + np2)) * 3;
      float gx = cent[g * 3], gy = cent[g * 3 + 1], gz = cent[g * 3 + 2];
      Abuf[buf][tid][128] = f2bf(p[0] - gx);
      Abuf[buf][tid][129] = f2bf(p[1] - gy);
      Abuf[buf][tid][130] = f2bf(p[2] - gz);
    }
  };

  __syncthreads();           // pad-zero visible before coord writes
  stage(0, 0);
  __syncthreads();

  for (int gi = 0; gi < 8; ++gi) {
    int cur = gi & 1;
    if (gi < 7) stage(gi + 1, cur ^ 1);

    f32x4 acc[4];
    #pragma unroll
    for (int nt = 0; nt < 4; ++nt) acc[nt] = (f32x4)0.0f;
    #pragma unroll
    for (int kt = 0; kt < 5; ++kt) {
      V8U a;
      a.s = *(const s16x8*)&Abuf[cur][lr][kt * 32 + q * 8];
      #pragma unroll
      for (int nt = 0; nt < 4; ++nt)
        acc[nt] = __builtin_amdgcn_mfma_f32_16x16x32_bf16(a.b, bfrag[nt][kt].b, acc[nt], 0, 0, 0);
    }
    int g = g0 + gi;
    #pragma unroll
    for (int nt = 0; nt < 4; ++nt) {
      float r0 = acc[nt][0], r1 = acc[nt][1], r2 = acc[nt][2], r3 = acc[nt][3];
      float mx = fmaxf(fmaxf(r0, r1), fmaxf(r2, r3));
      float mn = fminf(fminf(r0, r1), fminf(r2, r3));
      sum1[nt] += r0 + r1 + r2 + r3;
      sum2[nt] += r0 * r0 + r1 * r1 + r2 * r2 + r3 * r3;
      mx = fmaxf(mx, __shfl_xor(mx, 16)); mn = fminf(mn, __shfl_xor(mn, 16));
      mx = fmaxf(mx, __shfl_xor(mx, 32)); mn = fminf(mn, __shfl_xor(mn, 32));
      if (q == 0) {
        int col = w * 64 + nt * 16 + lr;
        wmax[(size_t)g * DOUT_CH + col] = mx;
        wmin[(size_t)g * DOUT_CH + col] = mn;
      }
    }
    __syncthreads();
  }
  #pragma unroll
  for (int nt = 0; nt < 4; ++nt) {
    float s1 = sum1[nt], s2 = sum2[nt];
    s1 += __shfl_xor(s1, 16); s2 += __shfl_xor(s2, 16);
    s1 += __shfl_xor(s1, 32); s2 += __shfl_xor(s2, 32);
    if (q == 0) {
      int col = w * 64 + nt * 16 + lr;
      psum[(size_t)col * GEMM_BLOCKS + blockIdx.x]   = s1;
      psumsq[(size_t)col * GEMM_BLOCKS + blockIdx.x] = s2;
    }
  }
}

// K4: reduce partials -> per-channel scale/shift (bias cancels in train BN)
__global__ __launch_bounds__(256)
void stats_kernel(const float* __restrict__ psum, const float* __restrict__ psumsq,
                  const float* __restrict__ gamma, const float* __restrict__ beta,
                  float* __restrict__ sc, float* __restrict__ tc)
{
  const int c = blockIdx.x;
  const int tid = threadIdx.x, lane = tid & 63, w = tid >> 6;
  float s1 = 0.f, s2 = 0.f;
  for (int r = tid; r < GEMM_BLOCKS; r += 256) {
    s1 += psum[(size_t)c * GEMM_BLOCKS + r];
    s2 += psumsq[(size_t)c * GEMM_BLOCKS + r];
  }
  #pragma unroll
  for (int off = 1; off < 64; off <<= 1) { s1 += __shfl_xor(s1, off); s2 += __shfl_xor(s2, off); }
  __shared__ float a1[4], a2[4];
  if (lane == 0) { a1[w] = s1; a2[w] = s2; }
  __syncthreads();
  if (tid == 0) {
    float S1 = a1[0] + a1[1] + a1[2] + a1[3];
    float S2 = a2[0] + a2[1] + a2[2] + a2[3];
    const float inv = 1.0f / (float)MROWS;
    float mean = S1 * inv;
    float var  = S2 * inv - mean * mean;
    float rs = rsqrtf(var + 1e-5f);
    float s = gamma[c] * rs;
    sc[c] = s;
    tc[c] = beta[c] - mean * s;
  }
}

// K5: out = relu(s * (s>0 ? max : min) + t)   (monotone-affine + relu + maxpool)
__global__ __launch_bounds__(256)
void final_kernel(const float* __restrict__ wmax, const float* __restrict__ wmin,
                  const float* __restrict__ sc, const float* __restrict__ tc,
                  float* __restrict__ out)
{
  int i4 = blockIdx.x * 256 + threadIdx.x;
  int base = i4 * 4;
  int c = base & (DOUT_CH - 1);
  float4 mx = *(const float4*)(wmax + base);
  float4 mn = *(const float4*)(wmin + base);
  float4 sv = *(const float4*)(sc + c);
  float4 tv = *(const float4*)(tc + c);
  float4 o;
  o.x = fmaxf(fmaf(sv.x, (sv.x > 0.f ? mx.x : mn.x), tv.x), 0.f);
  o.y = fmaxf(fmaf(sv.y, (sv.y > 0.f ? mx.y : mn.y), tv.y), 0.f);
  o.z = fmaxf(fmaf(sv.z, (sv.z > 0.f ? mx.z : mn.z), tv.z), 0.f);
  o.w = fmaxf(fmaf(sv.w, (sv.w > 0.f ? mx.w : mn.w), tv.w), 0.f);
  *(float4*)(out + base) = o;
}

extern "C" void kernel_launch(void* const* d_in, const int* in_sizes, int n_in,
                              void* d_out, int out_size, void* d_ws, size_t ws_size,
                              hipStream_t stream)
{
  const float* feature = (const float*)d_in[0];
  const float* coord   = (const float*)d_in[1];
  const float* W       = (const float*)d_in[2];
  // d_in[3] = conv bias: cancels exactly in train-mode BN -> unused
  const float* gamma   = (const float*)d_in[4];
  const float* beta    = (const float*)d_in[5];
  float* out = (float*)d_out;
  float* out_coord = out + OUT_FEAT_ELEMS;

  char* ws = (char*)d_ws;
  int*            nidx   = (int*)(ws + 0);                      // 1 MB
  unsigned short* Wb     = (unsigned short*)(ws + (1 << 20));   // 80 KB
  float*          psum   = (float*)(ws + (2 << 20));            // 2 MB
  float*          psumsq = (float*)(ws + (4 << 20));            // 2 MB
  float*          sc     = (float*)(ws + (6 << 20));            // 1 KB
  float*          tc     = (float*)(ws + (6 << 20) + 4096);     // 1 KB
  float*          wmax   = (float*)(ws + (8 << 20));            // 16 MB
  float*          wmin   = (float*)(ws + (8 << 20) + (size_t)OUT_FEAT_ELEMS * 4); // 16 MB

  hipLaunchKernelGGL(fps_wcast_kernel, dim3(BATCH + 1), dim3(512), 0, stream,
                     coord, W, out_coord, Wb);
  hipLaunchKernelGGL(knn_kernel, dim3(NGROUPS / 2), dim3(128), 0, stream,
                     coord, out_coord, nidx);
  hipLaunchKernelGGL(gemm_kernel, dim3(GEMM_BLOCKS), dim3(256), 0, stream,
                     feature, coord, out_coord, nidx, Wb, psum, psumsq, wmax, wmin);
  hipLaunchKernelGGL(stats_kernel, dim3(DOUT_CH), dim3(256), 0, stream,
                     psum, psumsq, gamma, beta, sc, tc);
  hipLaunchKernelGGL(final_kernel, dim3(OUT_FEAT_ELEMS / 1024), dim3(256), 0, stream,
                     wmax, wmin, sc, tc, out);
}

// Round 2
// 1118.479 us; speedup vs baseline: 1.6425x; 1.6425x over previous
//
#include <hip/hip_runtime.h>
#include <stdint.h>

// Problem constants
#define BATCH 16
#define NPTS 4096
#define DFEAT 128
#define NGRP 1024
#define KNNK 16
#define DOUT_CH 256
#define KPAD 160          // 131 padded to 5*32 for MFMA K
#define APAD 168          // LDS row stride (pad for banks)
#define NGROUPS (BATCH*NGRP)            // 16384
#define MROWS (NGROUPS*KNNK)            // 262144
#define GEMM_BLOCKS (NGROUPS/8)         // 2048
#define OUT_FEAT_ELEMS (NGROUPS*DOUT_CH) // 4194304

typedef __attribute__((ext_vector_type(8))) short s16x8;
typedef __attribute__((ext_vector_type(8))) __bf16 bf16x8;
typedef __attribute__((ext_vector_type(4))) float f32x4;

union V8U { s16x8 s; bf16x8 b; };

__device__ inline unsigned short f2bf(float f) {
  unsigned u = __float_as_uint(f);
  unsigned r = 0x7FFFu + ((u >> 16) & 1u);
  return (unsigned short)((u + r) >> 16);
}

// Bit-exact (vs jnp fp32, no-FMA) squared distance: ((dx*dx + dy*dy) + dz*dz)
__device__ inline float sqdist3(float ax, float ay, float az,
                                float bx, float by, float bz) {
  float dx = __fsub_rn(ax, bx);
  float dy = __fsub_rn(ay, by);
  float dz = __fsub_rn(az, bz);
  return __fadd_rn(__fadd_rn(__fmul_rn(dx, dx), __fmul_rn(dy, dy)), __fmul_rn(dz, dz));
}

__device__ inline unsigned long long shfl_xor_u64(unsigned long long v, int off) {
  unsigned hi = __shfl_xor((unsigned)(v >> 32), off);
  unsigned lo = __shfl_xor((unsigned)(v & 0xFFFFFFFFull), off);
  return ((unsigned long long)hi << 32) | lo;
}

__device__ inline unsigned long long u64max(unsigned long long a, unsigned long long b) {
  return a > b ? a : b;
}

// ---------------------------------------------------------------------------
// K1: FPS (blocks 0..15, one per batch) + W cast/permute/pad (block 16).
// Exact FPS; argmax with lowest-index tie-break done via a single u64-max
// reduction on packed keys (fbits<<32)|(~idx)  (dists >= 0 -> bits monotone).
// One __syncthreads per iteration; per-wave winners in double-buffered LDS
// slots reduced redundantly by every thread (no 2nd barrier, no serial scan).
// Center coords buffered in LDS and flushed once (no global-store drain on
// the barrier path).
// ---------------------------------------------------------------------------
__global__ __launch_bounds__(512)
void fps_wcast_kernel(const float* __restrict__ coord, const float* __restrict__ W,
                      float* __restrict__ out_coord, unsigned short* __restrict__ Wb)
{
  if (blockIdx.x >= BATCH) {
    // W: [256][131] fp32 -> Wb: [256][160] bf16, cols 0..127 = W[:,3:131] (features),
    // cols 128..130 = W[:,0:3] (coords), cols 131..159 = 0.
    for (int i = threadIdx.x; i < DOUT_CH * KPAD; i += 512) {
      int n = i / KPAD;
      int k = i - n * KPAD;
      float v = 0.f;
      if (k < 128)      v = W[n * 131 + 3 + k];
      else if (k < 131) v = W[n * 131 + (k - 128)];
      Wb[i] = f2bf(v);
    }
    return;
  }
  const int b = blockIdx.x;
  const int t = threadIdx.x;
  const int w = t >> 6;
  const int lane = t & 63;
  __shared__ float c3[NPTS * 3];                 // 48 KB
  __shared__ float ocb[NGRP * 3];                // 12 KB center coords buffer
  __shared__ unsigned long long slots[2][8];     // double-buffered per-wave winners

  { // coalesced load of this batch's coords into LDS (layout-preserving)
    const float4* g4 = (const float4*)(coord + (size_t)b * NPTS * 3);
    float4* l4 = (float4*)c3;
    #pragma unroll
    for (int qq = 0; qq < 6; ++qq) l4[t + 512 * qq] = g4[t + 512 * qq];
  }
  __syncthreads();

  // thread t owns points p = t + 512*j
  float px[8], py[8], pz[8], dist[8];
  unsigned lokey[8];
  #pragma unroll
  for (int j = 0; j < 8; ++j) {
    int p = t + 512 * j;
    px[j] = c3[3 * p]; py[j] = c3[3 * p + 1]; pz[j] = c3[3 * p + 2];
    dist[j] = __builtin_inff();
    lokey[j] = 0xFFFFFFFFu - (unsigned)p;        // bigger lo == smaller idx
  }

  if (t < 3) ocb[t] = c3[t];                     // sample 0 = point 0
  int last = 0;

  for (int i = 1; i < NGRP; ++i) {
    const int par = i & 1;
    float lx = c3[3 * last], ly = c3[3 * last + 1], lz = c3[3 * last + 2];

    unsigned long long cand[8];
    #pragma unroll
    for (int j = 0; j < 8; ++j) {
      float d  = sqdist3(px[j], py[j], pz[j], lx, ly, lz);
      float nd = fminf(dist[j], d);
      dist[j] = nd;
      cand[j] = ((unsigned long long)__float_as_uint(nd) << 32) | lokey[j];
    }
    // tree max over the 8 local candidates (short dependent chain)
    unsigned long long b0 = u64max(cand[0], cand[1]);
    unsigned long long b1 = u64max(cand[2], cand[3]);
    unsigned long long b2 = u64max(cand[4], cand[5]);
    unsigned long long b3 = u64max(cand[6], cand[7]);
    unsigned long long best = u64max(u64max(b0, b1), u64max(b2, b3));

    // wave reduction (u64 max == exact argmax + lowest-index tie-break)
    #pragma unroll
    for (int off = 1; off < 64; off <<= 1)
      best = u64max(best, shfl_xor_u64(best, off));

    if (lane == 0) slots[par][w] = best;
    __syncthreads();

    // every thread redundantly reduces the 8 per-wave winners
    unsigned long long f = slots[par][0];
    #pragma unroll
    for (int k = 1; k < 8; ++k) f = u64max(f, slots[par][k]);
    int mi = (int)(0xFFFFFFFFu - (unsigned)(f & 0xFFFFFFFFull));

    if (t < 3) ocb[3 * i + t] = c3[3 * mi + t];
    last = mi;
  }

  __syncthreads();
  // flush centers to global, coalesced
  float* oc = out_coord + (size_t)b * NGRP * 3;
  #pragma unroll
  for (int qq = 0; qq < 6; ++qq) oc[t + 512 * qq] = ocb[t + 512 * qq];
}

// ---------------------------------------------------------------------------
// K2: exact kNN (k=16). One wave per center; 2 centers per 128-thread block.
// Threshold T = 16th-smallest of per-lane minima (provable upper bound on true
// 16th distance) -> filter -> 16 exact argmin rounds with (d, idx) tie-break.
// ---------------------------------------------------------------------------
#define KNN_SLOTS 512
__global__ __launch_bounds__(128)
void knn_kernel(const float* __restrict__ coord, const float* __restrict__ cent,
                int* __restrict__ nidx)
{
  __shared__ float sd[2 * NPTS];
  __shared__ float svd[2 * KNN_SLOTS];
  __shared__ int   svi[2 * KNN_SLOTS];

  const int w = threadIdx.x >> 6;
  const int lane = threadIdx.x & 63;
  const int c = blockIdx.x * 2 + w;
  const int b = c >> 10;
  float* wd  = sd  + w * NPTS;
  float* wsd = svd + w * KNN_SLOTS;
  int*   wsi = svi + w * KNN_SLOTS;

  const float cx = cent[c * 3], cy = cent[c * 3 + 1], cz = cent[c * 3 + 2];
  const float* pc = coord + (size_t)b * NPTS * 3;

  float m = __builtin_inff();
  for (int tt = 0; tt < 64; ++tt) {
    int p = tt * 64 + lane;
    float d = sqdist3(cx, cy, cz, pc[3 * p], pc[3 * p + 1], pc[3 * p + 2]);
    wd[p] = d;
    m = fminf(m, d);
  }
  // radix-select the 16th smallest of the 64 lane minima (fp32 bits, all >= 0)
  unsigned mb = __float_as_uint(m);
  unsigned prefix = 0u;
  for (int bit = 30; bit >= 0; --bit) {
    unsigned trial = prefix | (1u << bit);
    unsigned long long ball = __ballot(mb < trial);
    if (__popcll(ball) < 16) prefix = trial;
  }
  const unsigned T = prefix;

  // compact survivors (d <= T); slot order == ascending point idx
  int base = 0;
  unsigned long long ltmask = (1ull << lane) - 1ull;
  for (int tt = 0; tt < 64; ++tt) {
    int p = tt * 64 + lane;
    float d = wd[p];
    bool keep = (__float_as_uint(d) <= T);
    unsigned long long mk = __ballot(keep);
    if (keep) {
      int pos = base + __popcll(mk & ltmask);
      if (pos < KNN_SLOTS) { wsd[pos] = d; wsi[pos] = p; }
    }
    base += __popcll(mk);
  }
  int S = base < KNN_SLOTS ? base : KNN_SLOTS;

  for (int r = 0; r < KNNK; ++r) {
    float bd = __builtin_inff(); int bs = 0x7fffffff;
    for (int s = lane; s < S; s += 64) {
      float d = wsd[s];
      if (d < bd) { bd = d; bs = s; }   // strict < keeps lowest slot/idx
    }
    #pragma unroll
    for (int off = 1; off < 64; off <<= 1) {
      float od = __shfl_xor(bd, off);
      int   os = __shfl_xor(bs, off);
      if (od < bd || (od == bd && os < bs)) { bd = od; bs = os; }
    }
    if (lane == 0) {
      nidx[c * KNNK + r] = wsi[bs];
      wsd[bs] = __builtin_inff();
    }
    __syncthreads();
  }
}

// ---------------------------------------------------------------------------
// K3: fused gather + bf16 MFMA GEMM + epilogue (max/min over K=16, channel
// sum/sumsq partials). Block = 8 groups (128 M-rows), 4 waves = 4x64 channels.
// W fragments held in registers; A (16x160 bf16) staged via LDS double-buffer.
// ---------------------------------------------------------------------------
__global__ __launch_bounds__(256)
void gemm_kernel(const float* __restrict__ feat, const float* __restrict__ coord,
                 const float* __restrict__ cent, const int* __restrict__ nidx,
                 const unsigned short* __restrict__ Wb,
                 float* __restrict__ psum, float* __restrict__ psumsq,
                 float* __restrict__ wmax, float* __restrict__ wmin)
{
  __shared__ unsigned short Abuf[2][16][APAD];
  const int tid = threadIdx.x;
  const int w = tid >> 6, lane = tid & 63;
  const int lr = lane & 15, q = lane >> 4;
  const int g0 = blockIdx.x * 8;
  const int b = g0 >> 10;

  // zero cols 128..159 of both buffers once (coords overwrite 128..130 per group)
  for (int i = tid; i < 2 * 16 * 32; i += 256) {
    int buf = i >> 9, rr = (i >> 5) & 15, cc = 128 + (i & 31);
    Abuf[buf][rr][cc] = 0;
  }

  // B fragments: B[k][n] supplied as Wb[n][k] row chunks (16B per lane)
  V8U bfrag[4][5];
  #pragma unroll
  for (int nt = 0; nt < 4; ++nt)
    #pragma unroll
    for (int kt = 0; kt < 5; ++kt) {
      int n = w * 64 + nt * 16 + lr;
      bfrag[nt][kt].s = *(const s16x8*)(Wb + n * KPAD + kt * 32 + q * 8);
    }

  float sum1[4] = {0, 0, 0, 0}, sum2[4] = {0, 0, 0, 0};

  auto stage = [&](int gi, int buf) {
    int g = g0 + gi;
    int r = tid >> 4, c16 = tid & 15;
    int np = nidx[g * 16 + r];
    const float* fr = feat + ((size_t)(b * NPTS + np)) * DFEAT + c16 * 8;
    float4 f0 = ((const float4*)fr)[0];
    float4 f1 = ((const float4*)fr)[1];
    s16x8 v;
    v[0] = f2bf(f0.x); v[1] = f2bf(f0.y); v[2] = f2bf(f0.z); v[3] = f2bf(f0.w);
    v[4] = f2bf(f1.x); v[5] = f2bf(f1.y); v[6] = f2bf(f1.z); v[7] = f2bf(f1.w);
    *(s16x8*)&Abuf[buf][r][c16 * 8] = v;
    if (tid < 16) {
      int np2 = nidx[g * 16 + tid];
      const float* p = coord + ((size_t)(b * NPTS + np2)) * 3;
      float gx = cent[g * 3], gy = cent[g * 3 + 1], gz = cent[g * 3 + 2];
      Abuf[buf][tid][128] = f2bf(p[0] - gx);
      Abuf[buf][tid][129] = f2bf(p[1] - gy);
      Abuf[buf][tid][130] = f2bf(p[2] - gz);
    }
  };

  __syncthreads();           // pad-zero visible before coord writes
  stage(0, 0);
  __syncthreads();

  for (int gi = 0; gi < 8; ++gi) {
    int cur = gi & 1;
    if (gi < 7) stage(gi + 1, cur ^ 1);

    f32x4 acc[4];
    #pragma unroll
    for (int nt = 0; nt < 4; ++nt) acc[nt] = (f32x4)0.0f;
    #pragma unroll
    for (int kt = 0; kt < 5; ++kt) {
      V8U a;
      a.s = *(const s16x8*)&Abuf[cur][lr][kt * 32 + q * 8];
      #pragma unroll
      for (int nt = 0; nt < 4; ++nt)
        acc[nt] = __builtin_amdgcn_mfma_f32_16x16x32_bf16(a.b, bfrag[nt][kt].b, acc[nt], 0, 0, 0);
    }
    int g = g0 + gi;
    #pragma unroll
    for (int nt = 0; nt < 4; ++nt) {
      float r0 = acc[nt][0], r1 = acc[nt][1], r2 = acc[nt][2], r3 = acc[nt][3];
      float mx = fmaxf(fmaxf(r0, r1), fmaxf(r2, r3));
      float mn = fminf(fminf(r0, r1), fminf(r2, r3));
      sum1[nt] += r0 + r1 + r2 + r3;
      sum2[nt] += r0 * r0 + r1 * r1 + r2 * r2 + r3 * r3;
      mx = fmaxf(mx, __shfl_xor(mx, 16)); mn = fminf(mn, __shfl_xor(mn, 16));
      mx = fmaxf(mx, __shfl_xor(mx, 32)); mn = fminf(mn, __shfl_xor(mn, 32));
      if (q == 0) {
        int col = w * 64 + nt * 16 + lr;
        wmax[(size_t)g * DOUT_CH + col] = mx;
        wmin[(size_t)g * DOUT_CH + col] = mn;
      }
    }
    __syncthreads();
  }
  #pragma unroll
  for (int nt = 0; nt < 4; ++nt) {
    float s1 = sum1[nt], s2 = sum2[nt];
    s1 += __shfl_xor(s1, 16); s2 += __shfl_xor(s2, 16);
    s1 += __shfl_xor(s1, 32); s2 += __shfl_xor(s2, 32);
    if (q == 0) {
      int col = w * 64 + nt * 16 + lr;
      psum[(size_t)col * GEMM_BLOCKS + blockIdx.x]   = s1;
      psumsq[(size_t)col * GEMM_BLOCKS + blockIdx.x] = s2;
    }
  }
}

// K4: reduce partials -> per-channel scale/shift (bias cancels in train BN)
__global__ __launch_bounds__(256)
void stats_kernel(const float* __restrict__ psum, const float* __restrict__ psumsq,
                  const float* __restrict__ gamma, const float* __restrict__ beta,
                  float* __restrict__ sc, float* __restrict__ tc)
{
  const int c = blockIdx.x;
  const int tid = threadIdx.x, lane = tid & 63, w = tid >> 6;
  float s1 = 0.f, s2 = 0.f;
  for (int r = tid; r < GEMM_BLOCKS; r += 256) {
    s1 += psum[(size_t)c * GEMM_BLOCKS + r];
    s2 += psumsq[(size_t)c * GEMM_BLOCKS + r];
  }
  #pragma unroll
  for (int off = 1; off < 64; off <<= 1) { s1 += __shfl_xor(s1, off); s2 += __shfl_xor(s2, off); }
  __shared__ float a1[4], a2[4];
  if (lane == 0) { a1[w] = s1; a2[w] = s2; }
  __syncthreads();
  if (tid == 0) {
    float S1 = a1[0] + a1[1] + a1[2] + a1[3];
    float S2 = a2[0] + a2[1] + a2[2] + a2[3];
    const float inv = 1.0f / (float)MROWS;
    float mean = S1 * inv;
    float var  = S2 * inv - mean * mean;
    float rs = rsqrtf(var + 1e-5f);
    float s = gamma[c] * rs;
    sc[c] = s;
    tc[c] = beta[c] - mean * s;
  }
}

// K5: out = relu(s * (s>0 ? max : min) + t)   (monotone-affine + relu + maxpool)
__global__ __launch_bounds__(256)
void final_kernel(const float* __restrict__ wmax, const float* __restrict__ wmin,
                  const float* __restrict__ sc, const float* __restrict__ tc,
                  float* __restrict__ out)
{
  int i4 = blockIdx.x * 256 + threadIdx.x;
  int base = i4 * 4;
  int c = base & (DOUT_CH - 1);
  float4 mx = *(const float4*)(wmax + base);
  float4 mn = *(const float4*)(wmin + base);
  float4 sv = *(const float4*)(sc + c);
  float4 tv = *(const float4*)(tc + c);
  float4 o;
  o.x = fmaxf(fmaf(sv.x, (sv.x > 0.f ? mx.x : mn.x), tv.x), 0.f);
  o.y = fmaxf(fmaf(sv.y, (sv.y > 0.f ? mx.y : mn.y), tv.y), 0.f);
  o.z = fmaxf(fmaf(sv.z, (sv.z > 0.f ? mx.z : mn.z), tv.z), 0.f);
  o.w = fmaxf(fmaf(sv.w, (sv.w > 0.f ? mx.w : mn.w), tv.w), 0.f);
  *(float4*)(out + base) = o;
}

extern "C" void kernel_launch(void* const* d_in, const int* in_sizes, int n_in,
                              void* d_out, int out_size, void* d_ws, size_t ws_size,
                              hipStream_t stream)
{
  const float* feature = (const float*)d_in[0];
  const float* coord   = (const float*)d_in[1];
  const float* W       = (const float*)d_in[2];
  // d_in[3] = conv bias: cancels exactly in train-mode BN -> unused
  const float* gamma   = (const float*)d_in[4];
  const float* beta    = (const float*)d_in[5];
  float* out = (float*)d_out;
  float* out_coord = out + OUT_FEAT_ELEMS;

  char* ws = (char*)d_ws;
  int*            nidx   = (int*)(ws + 0);                      // 1 MB
  unsigned short* Wb     = (unsigned short*)(ws + (1 << 20));   // 80 KB
  float*          psum   = (float*)(ws + (2 << 20));            // 2 MB
  float*          psumsq = (float*)(ws + (4 << 20));            // 2 MB
  float*          sc     = (float*)(ws + (6 << 20));            // 1 KB
  float*          tc     = (float*)(ws + (6 << 20) + 4096);     // 1 KB
  float*          wmax   = (float*)(ws + (8 << 20));            // 16 MB
  float*          wmin   = (float*)(ws + (8 << 20) + (size_t)OUT_FEAT_ELEMS * 4); // 16 MB

  hipLaunchKernelGGL(fps_wcast_kernel, dim3(BATCH + 1), dim3(512), 0, stream,
                     coord, W, out_coord, Wb);
  hipLaunchKernelGGL(knn_kernel, dim3(NGROUPS / 2), dim3(128), 0, stream,
                     coord, out_coord, nidx);
  hipLaunchKernelGGL(gemm_kernel, dim3(GEMM_BLOCKS), dim3(256), 0, stream,
                     feature, coord, out_coord, nidx, Wb, psum, psumsq, wmax, wmin);
  hipLaunchKernelGGL(stats_kernel, dim3(DOUT_CH), dim3(256), 0, stream,
                     psum, psumsq, gamma, beta, sc, tc);
  hipLaunchKernelGGL(final_kernel, dim3(OUT_FEAT_ELEMS / 1024), dim3(256), 0, stream,
                     wmax, wmin, sc, tc, out);
}

// Round 3
// 959.983 us; speedup vs baseline: 1.9137x; 1.1651x over previous
//
#include <hip/hip_runtime.h>
#include <stdint.h>

// Problem constants
#define BATCH 16
#define NPTS 4096
#define DFEAT 128
#define NGRP 1024
#define KNNK 16
#define DOUT_CH 256
#define KPAD 160          // 131 padded to 5*32 for MFMA K
#define APAD 168          // LDS row stride (pad for banks)
#define NGROUPS (BATCH*NGRP)            // 16384
#define MROWS (NGROUPS*KNNK)            // 262144
#define GEMM_BLOCKS (NGROUPS/8)         // 2048
#define OUT_FEAT_ELEMS (NGROUPS*DOUT_CH) // 4194304

typedef __attribute__((ext_vector_type(8))) short s16x8;
typedef __attribute__((ext_vector_type(8))) __bf16 bf16x8;
typedef __attribute__((ext_vector_type(4))) float f32x4;

union V8U { s16x8 s; bf16x8 b; };

__device__ inline unsigned short f2bf(float f) {
  unsigned u = __float_as_uint(f);
  unsigned r = 0x7FFFu + ((u >> 16) & 1u);
  return (unsigned short)((u + r) >> 16);
}

// Bit-exact (vs fp32 numpy ref, no-FMA) squared distance: ((dx*dx + dy*dy) + dz*dz)
__device__ inline float sqdist3(float ax, float ay, float az,
                                float bx, float by, float bz) {
  float dx = __fsub_rn(ax, bx);
  float dy = __fsub_rn(ay, by);
  float dz = __fsub_rn(az, bz);
  return __fadd_rn(__fadd_rn(__fmul_rn(dx, dx), __fmul_rn(dy, dy)), __fmul_rn(dz, dz));
}

__device__ inline unsigned long long u64max(unsigned long long a, unsigned long long b) {
  return a > b ? a : b;
}

// One DPP max-reduction step on a u64 key (2x 32-bit DPP movs + u64 compare).
// bound_ctrl=true: invalid-source lanes read 0, and 0 never wins (keys > 0).
template<int CTRL>
__device__ inline unsigned long long dpp_max_step(unsigned long long k) {
  unsigned hi = (unsigned)(k >> 32), lo = (unsigned)k;
  unsigned hi2 = (unsigned)__builtin_amdgcn_update_dpp(0, (int)hi, CTRL, 0xF, 0xF, true);
  unsigned lo2 = (unsigned)__builtin_amdgcn_update_dpp(0, (int)lo, CTRL, 0xF, 0xF, true);
  unsigned long long k2 = ((unsigned long long)hi2 << 32) | lo2;
  return k2 > k ? k2 : k;
}

// Full wave64 max-reduce: result valid in lane 63.
__device__ inline unsigned long long wave_max_u64(unsigned long long k) {
  k = dpp_max_step<0xB1>(k);   // quad_perm [1,0,3,2]  (xor 1)
  k = dpp_max_step<0x4E>(k);   // quad_perm [2,3,0,1]  (xor 2)
  k = dpp_max_step<0x141>(k);  // row_half_mirror      (xor 4 class)
  k = dpp_max_step<0x140>(k);  // row_mirror           (xor 8 class, row16 done)
  k = dpp_max_step<0x142>(k);  // row_bcast15          (lane31 = max 0..31, lane63 = max 32..63)
  k = dpp_max_step<0x143>(k);  // row_bcast31          (lane63 = max 0..63)
  return k;
}

// ---------------------------------------------------------------------------
// K1: FPS (blocks 0..15, one per batch) + W cast/permute/pad (block 16).
// Exact FPS; argmax with lowest-index tie-break via u64-max on packed keys
// (fbits<<32)|(~idx). In-wave reduction uses DPP (VALU latency) instead of
// ds_bpermute shuffles; coords live in LDS as float4 (one ds_read_b128 to
// fetch the winner). One barrier per iteration; 8 per-wave winners in
// double-buffered LDS slots reduced redundantly by every thread.
// ---------------------------------------------------------------------------
__global__ __launch_bounds__(512)
void fps_wcast_kernel(const float* __restrict__ coord, const float* __restrict__ W,
                      float* __restrict__ out_coord, unsigned short* __restrict__ Wb)
{
  if (blockIdx.x >= BATCH) {
    // W: [256][131] fp32 -> Wb: [256][160] bf16, cols 0..127 = W[:,3:131] (features),
    // cols 128..130 = W[:,0:3] (coords), cols 131..159 = 0.
    for (int i = threadIdx.x; i < DOUT_CH * KPAD; i += 512) {
      int n = i / KPAD;
      int k = i - n * KPAD;
      float v = 0.f;
      if (k < 128)      v = W[n * 131 + 3 + k];
      else if (k < 131) v = W[n * 131 + (k - 128)];
      Wb[i] = f2bf(v);
    }
    return;
  }
  const int b = blockIdx.x;
  const int t = threadIdx.x;
  const int w = t >> 6;
  const int lane = t & 63;
  __shared__ float4 c4[NPTS];                    // 64 KB, coords padded to 16 B
  __shared__ float ocb[NGRP * 3];                // 12 KB center coords buffer
  __shared__ unsigned long long slots[2][8];     // double-buffered per-wave winners

  { // load this batch's coords into LDS float4 layout
    const float* g = coord + (size_t)b * NPTS * 3;
    for (int p = t; p < NPTS; p += 512)
      c4[p] = make_float4(g[3 * p], g[3 * p + 1], g[3 * p + 2], 0.f);
  }
  __syncthreads();

  // thread t owns points p = t + 512*j
  float px[8], py[8], pz[8], dist[8];
  unsigned lokey[8];
  #pragma unroll
  for (int j = 0; j < 8; ++j) {
    int p = t + 512 * j;
    float4 c = c4[p];
    px[j] = c.x; py[j] = c.y; pz[j] = c.z;
    dist[j] = __builtin_inff();
    lokey[j] = 0xFFFFFFFFu - (unsigned)p;        // bigger lo == smaller idx
  }

  float lx = c4[0].x, ly = c4[0].y, lz = c4[0].z;
  if (t == 0) { ocb[0] = lx; ocb[1] = ly; ocb[2] = lz; }

  for (int i = 1; i < NGRP; ++i) {
    const int par = i & 1;

    unsigned long long cand[8];
    #pragma unroll
    for (int j = 0; j < 8; ++j) {
      float d  = sqdist3(px[j], py[j], pz[j], lx, ly, lz);
      float nd = fminf(dist[j], d);
      dist[j] = nd;
      cand[j] = ((unsigned long long)__float_as_uint(nd) << 32) | lokey[j];
    }
    // tree max over the 8 local candidates (short dependent chain)
    unsigned long long b0 = u64max(cand[0], cand[1]);
    unsigned long long b1 = u64max(cand[2], cand[3]);
    unsigned long long b2 = u64max(cand[4], cand[5]);
    unsigned long long b3 = u64max(cand[6], cand[7]);
    unsigned long long best = u64max(u64max(b0, b1), u64max(b2, b3));

    // in-wave reduce via DPP (lane 63 holds the wave winner)
    best = wave_max_u64(best);
    if (lane == 63) slots[par][w] = best;
    __syncthreads();

    // every thread redundantly reduces the 8 per-wave winners
    unsigned long long f = slots[par][0];
    #pragma unroll
    for (int k = 1; k < 8; ++k) f = u64max(f, slots[par][k]);
    int mi = (int)(0xFFFFFFFFu - (unsigned)(f & 0xFFFFFFFFull));

    float4 cw = c4[mi];
    lx = cw.x; ly = cw.y; lz = cw.z;
    if (t < 3) ocb[3 * i + t] = (t == 0) ? cw.x : ((t == 1) ? cw.y : cw.z);
  }

  __syncthreads();
  // flush centers to global, coalesced
  float* oc = out_coord + (size_t)b * NGRP * 3;
  #pragma unroll
  for (int qq = 0; qq < 6; ++qq) oc[t + 512 * qq] = ocb[t + 512 * qq];
}

// ---------------------------------------------------------------------------
// K2: exact kNN (k=16). One wave per center; 2 centers per 128-thread block.
// Threshold T = 16th-smallest of per-lane minima (provable upper bound on true
// 16th distance) -> filter -> 16 exact argmin rounds with (d, idx) tie-break.
// ---------------------------------------------------------------------------
#define KNN_SLOTS 512
__global__ __launch_bounds__(128)
void knn_kernel(const float* __restrict__ coord, const float* __restrict__ cent,
                int* __restrict__ nidx)
{
  __shared__ float sd[2 * NPTS];
  __shared__ float svd[2 * KNN_SLOTS];
  __shared__ int   svi[2 * KNN_SLOTS];

  const int w = threadIdx.x >> 6;
  const int lane = threadIdx.x & 63;
  const int c = blockIdx.x * 2 + w;
  const int b = c >> 10;
  float* wd  = sd  + w * NPTS;
  float* wsd = svd + w * KNN_SLOTS;
  int*   wsi = svi + w * KNN_SLOTS;

  const float cx = cent[c * 3], cy = cent[c * 3 + 1], cz = cent[c * 3 + 2];
  const float* pc = coord + (size_t)b * NPTS * 3;

  float m = __builtin_inff();
  for (int tt = 0; tt < 64; ++tt) {
    int p = tt * 64 + lane;
    float d = sqdist3(cx, cy, cz, pc[3 * p], pc[3 * p + 1], pc[3 * p + 2]);
    wd[p] = d;
    m = fminf(m, d);
  }
  // radix-select the 16th smallest of the 64 lane minima (fp32 bits, all >= 0)
  unsigned mb = __float_as_uint(m);
  unsigned prefix = 0u;
  for (int bit = 30; bit >= 0; --bit) {
    unsigned trial = prefix | (1u << bit);
    unsigned long long ball = __ballot(mb < trial);
    if (__popcll(ball) < 16) prefix = trial;
  }
  const unsigned T = prefix;

  // compact survivors (d <= T); slot order == ascending point idx
  int base = 0;
  unsigned long long ltmask = (1ull << lane) - 1ull;
  for (int tt = 0; tt < 64; ++tt) {
    int p = tt * 64 + lane;
    float d = wd[p];
    bool keep = (__float_as_uint(d) <= T);
    unsigned long long mk = __ballot(keep);
    if (keep) {
      int pos = base + __popcll(mk & ltmask);
      if (pos < KNN_SLOTS) { wsd[pos] = d; wsi[pos] = p; }
    }
    base += __popcll(mk);
  }
  int S = base < KNN_SLOTS ? base : KNN_SLOTS;

  for (int r = 0; r < KNNK; ++r) {
    float bd = __builtin_inff(); int bs = 0x7fffffff;
    for (int s = lane; s < S; s += 64) {
      float d = wsd[s];
      if (d < bd) { bd = d; bs = s; }   // strict < keeps lowest slot/idx
    }
    #pragma unroll
    for (int off = 1; off < 64; off <<= 1) {
      float od = __shfl_xor(bd, off);
      int   os = __shfl_xor(bs, off);
      if (od < bd || (od == bd && os < bs)) { bd = od; bs = os; }
    }
    if (lane == 0) {
      nidx[c * KNNK + r] = wsi[bs];
      wsd[bs] = __builtin_inff();
    }
    __syncthreads();
  }
}

// ---------------------------------------------------------------------------
// K3: fused gather + bf16 MFMA GEMM + epilogue (max/min over K=16, channel
// sum/sumsq partials). Block = 8 groups (128 M-rows), 4 waves = 4x64 channels.
// W fragments held in registers; A (16x160 bf16) staged via LDS double-buffer.
// ---------------------------------------------------------------------------
__global__ __launch_bounds__(256)
void gemm_kernel(const float* __restrict__ feat, const float* __restrict__ coord,
                 const float* __restrict__ cent, const int* __restrict__ nidx,
                 const unsigned short* __restrict__ Wb,
                 float* __restrict__ psum, float* __restrict__ psumsq,
                 float* __restrict__ wmax, float* __restrict__ wmin)
{
  __shared__ unsigned short Abuf[2][16][APAD];
  const int tid = threadIdx.x;
  const int w = tid >> 6, lane = tid & 63;
  const int lr = lane & 15, q = lane >> 4;
  const int g0 = blockIdx.x * 8;
  const int b = g0 >> 10;

  // zero cols 128..159 of both buffers once (coords overwrite 128..130 per group)
  for (int i = tid; i < 2 * 16 * 32; i += 256) {
    int buf = i >> 9, rr = (i >> 5) & 15, cc = 128 + (i & 31);
    Abuf[buf][rr][cc] = 0;
  }

  // B fragments: B[k][n] supplied as Wb[n][k] row chunks (16B per lane)
  V8U bfrag[4][5];
  #pragma unroll
  for (int nt = 0; nt < 4; ++nt)
    #pragma unroll
    for (int kt = 0; kt < 5; ++kt) {
      int n = w * 64 + nt * 16 + lr;
      bfrag[nt][kt].s = *(const s16x8*)(Wb + n * KPAD + kt * 32 + q * 8);
    }

  float sum1[4] = {0, 0, 0, 0}, sum2[4] = {0, 0, 0, 0};

  auto stage = [&](int gi, int buf) {
    int g = g0 + gi;
    int r = tid >> 4, c16 = tid & 15;
    int np = nidx[g * 16 + r];
    const float* fr = feat + ((size_t)(b * NPTS + np)) * DFEAT + c16 * 8;
    float4 f0 = ((const float4*)fr)[0];
    float4 f1 = ((const float4*)fr)[1];
    s16x8 v;
    v[0] = f2bf(f0.x); v[1] = f2bf(f0.y); v[2] = f2bf(f0.z); v[3] = f2bf(f0.w);
    v[4] = f2bf(f1.x); v[5] = f2bf(f1.y); v[6] = f2bf(f1.z); v[7] = f2bf(f1.w);
    *(s16x8*)&Abuf[buf][r][c16 * 8] = v;
    if (tid < 16) {
      int np2 = nidx[g * 16 + tid];
      const float* p = coord + ((size_t)(b * NPTS + np2)) * 3;
      float gx = cent[g * 3], gy = cent[g * 3 + 1], gz = cent[g * 3 + 2];
      Abuf[buf][tid][128] = f2bf(p[0] - gx);
      Abuf[buf][tid][129] = f2bf(p[1] - gy);
      Abuf[buf][tid][130] = f2bf(p[2] - gz);
    }
  };

  __syncthreads();           // pad-zero visible before coord writes
  stage(0, 0);
  __syncthreads();

  for (int gi = 0; gi < 8; ++gi) {
    int cur = gi & 1;
    if (gi < 7) stage(gi + 1, cur ^ 1);

    f32x4 acc[4];
    #pragma unroll
    for (int nt = 0; nt < 4; ++nt) acc[nt] = (f32x4)0.0f;
    #pragma unroll
    for (int kt = 0; kt < 5; ++kt) {
      V8U a;
      a.s = *(const s16x8*)&Abuf[cur][lr][kt * 32 + q * 8];
      #pragma unroll
      for (int nt = 0; nt < 4; ++nt)
        acc[nt] = __builtin_amdgcn_mfma_f32_16x16x32_bf16(a.b, bfrag[nt][kt].b, acc[nt], 0, 0, 0);
    }
    int g = g0 + gi;
    #pragma unroll
    for (int nt = 0; nt < 4; ++nt) {
      float r0 = acc[nt][0], r1 = acc[nt][1], r2 = acc[nt][2], r3 = acc[nt][3];
      float mx = fmaxf(fmaxf(r0, r1), fmaxf(r2, r3));
      float mn = fminf(fminf(r0, r1), fminf(r2, r3));
      sum1[nt] += r0 + r1 + r2 + r3;
      sum2[nt] += r0 * r0 + r1 * r1 + r2 * r2 + r3 * r3;
      mx = fmaxf(mx, __shfl_xor(mx, 16)); mn = fminf(mn, __shfl_xor(mn, 16));
      mx = fmaxf(mx, __shfl_xor(mx, 32)); mn = fminf(mn, __shfl_xor(mn, 32));
      if (q == 0) {
        int col = w * 64 + nt * 16 + lr;
        wmax[(size_t)g * DOUT_CH + col] = mx;
        wmin[(size_t)g * DOUT_CH + col] = mn;
      }
    }
    __syncthreads();
  }
  #pragma unroll
  for (int nt = 0; nt < 4; ++nt) {
    float s1 = sum1[nt], s2 = sum2[nt];
    s1 += __shfl_xor(s1, 16); s2 += __shfl_xor(s2, 16);
    s1 += __shfl_xor(s1, 32); s2 += __shfl_xor(s2, 32);
    if (q == 0) {
      int col = w * 64 + nt * 16 + lr;
      psum[(size_t)col * GEMM_BLOCKS + blockIdx.x]   = s1;
      psumsq[(size_t)col * GEMM_BLOCKS + blockIdx.x] = s2;
    }
  }
}

// K4: reduce partials -> per-channel scale/shift (bias cancels in train BN)
__global__ __launch_bounds__(256)
void stats_kernel(const float* __restrict__ psum, const float* __restrict__ psumsq,
                  const float* __restrict__ gamma, const float* __restrict__ beta,
                  float* __restrict__ sc, float* __restrict__ tc)
{
  const int c = blockIdx.x;
  const int tid = threadIdx.x, lane = tid & 63, w = tid >> 6;
  float s1 = 0.f, s2 = 0.f;
  for (int r = tid; r < GEMM_BLOCKS; r += 256) {
    s1 += psum[(size_t)c * GEMM_BLOCKS + r];
    s2 += psumsq[(size_t)c * GEMM_BLOCKS + r];
  }
  #pragma unroll
  for (int off = 1; off < 64; off <<= 1) { s1 += __shfl_xor(s1, off); s2 += __shfl_xor(s2, off); }
  __shared__ float a1[4], a2[4];
  if (lane == 0) { a1[w] = s1; a2[w] = s2; }
  __syncthreads();
  if (tid == 0) {
    float S1 = a1[0] + a1[1] + a1[2] + a1[3];
    float S2 = a2[0] + a2[1] + a2[2] + a2[3];
    const float inv = 1.0f / (float)MROWS;
    float mean = S1 * inv;
    float var  = S2 * inv - mean * mean;
    float rs = rsqrtf(var + 1e-5f);
    float s = gamma[c] * rs;
    sc[c] = s;
    tc[c] = beta[c] - mean * s;
  }
}

// K5: out = relu(s * (s>0 ? max : min) + t)   (monotone-affine + relu + maxpool)
__global__ __launch_bounds__(256)
void final_kernel(const float* __restrict__ wmax, const float* __restrict__ wmin,
                  const float* __restrict__ sc, const float* __restrict__ tc,
                  float* __restrict__ out)
{
  int i4 = blockIdx.x * 256 + threadIdx.x;
  int base = i4 * 4;
  int c = base & (DOUT_CH - 1);
  float4 mx = *(const float4*)(wmax + base);
  float4 mn = *(const float4*)(wmin + base);
  float4 sv = *(const float4*)(sc + c);
  float4 tv = *(const float4*)(tc + c);
  float4 o;
  o.x = fmaxf(fmaf(sv.x, (sv.x > 0.f ? mx.x : mn.x), tv.x), 0.f);
  o.y = fmaxf(fmaf(sv.y, (sv.y > 0.f ? mx.y : mn.y), tv.y), 0.f);
  o.z = fmaxf(fmaf(sv.z, (sv.z > 0.f ? mx.z : mn.z), tv.z), 0.f);
  o.w = fmaxf(fmaf(sv.w, (sv.w > 0.f ? mx.w : mn.w), tv.w), 0.f);
  *(float4*)(out + base) = o;
}

extern "C" void kernel_launch(void* const* d_in, const int* in_sizes, int n_in,
                              void* d_out, int out_size, void* d_ws, size_t ws_size,
                              hipStream_t stream)
{
  const float* feature = (const float*)d_in[0];
  const float* coord   = (const float*)d_in[1];
  const float* W       = (const float*)d_in[2];
  // d_in[3] = conv bias: cancels exactly in train-mode BN -> unused
  const float* gamma   = (const float*)d_in[4];
  const float* beta    = (const float*)d_in[5];
  float* out = (float*)d_out;
  float* out_coord = out + OUT_FEAT_ELEMS;

  char* ws = (char*)d_ws;
  int*            nidx   = (int*)(ws + 0);                      // 1 MB
  unsigned short* Wb     = (unsigned short*)(ws + (1 << 20));   // 80 KB
  float*          psum   = (float*)(ws + (2 << 20));            // 2 MB
  float*          psumsq = (float*)(ws + (4 << 20));            // 2 MB
  float*          sc     = (float*)(ws + (6 << 20));            // 1 KB
  float*          tc     = (float*)(ws + (6 << 20) + 4096);     // 1 KB
  float*          wmax   = (float*)(ws + (8 << 20));            // 16 MB
  float*          wmin   = (float*)(ws + (8 << 20) + (size_t)OUT_FEAT_ELEMS * 4); // 16 MB

  hipLaunchKernelGGL(fps_wcast_kernel, dim3(BATCH + 1), dim3(512), 0, stream,
                     coord, W, out_coord, Wb);
  hipLaunchKernelGGL(knn_kernel, dim3(NGROUPS / 2), dim3(128), 0, stream,
                     coord, out_coord, nidx);
  hipLaunchKernelGGL(gemm_kernel, dim3(GEMM_BLOCKS), dim3(256), 0, stream,
                     feature, coord, out_coord, nidx, Wb, psum, psumsq, wmax, wmin);
  hipLaunchKernelGGL(stats_kernel, dim3(DOUT_CH), dim3(256), 0, stream,
                     psum, psumsq, gamma, beta, sc, tc);
  hipLaunchKernelGGL(final_kernel, dim3(OUT_FEAT_ELEMS / 1024), dim3(256), 0, stream,
                     wmax, wmin, sc, tc, out);
}